// Round 8
// baseline (627.256 us; speedup 1.0000x reference)
//
#include <hip/hip_runtime.h>
#include <hip/hip_cooperative_groups.h>
#include <hip/hip_bf16.h>
#include <cstdint>
#include <cstddef>

// B=4, LQ=LK=1024, D=512, H=8. fp32 in/out; bf16 MFMA compute.
// R14: single cooperative persistent kernel. Phases (verbatim R13 bodies):
//   P1 prep -> P2 combine(Mt,U) -> P3 stage2(t,VWT) -> P4 big(scores)
//   -> P5 pvw -> P6 reduce4, separated by grid.sync() instead of 5 dispatch
// boundaries (~10us each; R13 showed ~60us of inter-dispatch time).
// Engine: proven 2-barrier 128x128 tile, 32KB LDS, chunk^(row&7) swizzle.

typedef __bf16 bf16;
typedef __bf16 bf16x4 __attribute__((ext_vector_type(4)));
typedef __bf16 bf16x8 __attribute__((ext_vector_type(8)));
typedef float f32x4 __attribute__((ext_vector_type(4)));

namespace cg = cooperative_groups;

__device__ inline void gload_lds16(const void* g, void* l) {
  __builtin_amdgcn_global_load_lds(
      (const __attribute__((address_space(1))) void*)g,
      (__attribute__((address_space(3))) void*)l, 16, 0, 0);
}

// Tile body: C[128,128] at (m0,n0) of scale*(A . B^T). BK=64, 256 thr.
// LDS swizzle: global 16B-chunk c of row r lives at slot c ^ (r&7).
// MODE 0: C = acc*scale (CT). MODE 1: P = maskbit ? exp(acc*scale) : 0 (bf16)
// + atomicAdd row sums. (verbatim R7/R13 body — 0 conflicts, best measured)
template <typename CT, int MODE>
__device__ __forceinline__ void gemm_body(
    bf16* As, bf16* Bs,
    const bf16* __restrict__ A, const bf16* __restrict__ B, CT* __restrict__ C,
    int K, int lda, int ldb, int ldc, int m0, int n0, float scale,
    const unsigned* __restrict__ mrow, float* __restrict__ sumrow)
{
  const int t = threadIdx.x;
  const int lane = t & 63, w = t >> 6;
  const int wm = w >> 1, wn = w & 1;

  const int srow = t >> 3;                       // 0..31
  const int schunk = (t & 7) ^ (srow & 7);       // swizzled source chunk
  const bf16* Ag = A + (size_t)(m0 + srow) * lda + schunk * 8;
  const bf16* Bg = B + (size_t)(n0 + srow) * ldb + schunk * 8;
  bf16* Als = As + t * 8;
  bf16* Bls = Bs + t * 8;

  f32x4 acc[4][4] = {};
  const int rr = lane & 15;
  const int q4 = lane >> 4;

  const int kIters = K >> 6;
  for (int kt = 0; kt < kIters; ++kt) {
    __syncthreads();
#pragma unroll
    for (int i = 0; i < 4; ++i) {
      gload_lds16(Ag + (size_t)(32 * i) * lda, Als + i * 2048);
      gload_lds16(Bg + (size_t)(32 * i) * ldb, Bls + i * 2048);
    }
    Ag += 64; Bg += 64;
    __syncthreads();

#pragma unroll
    for (int kk = 0; kk < 2; ++kk) {
      bf16x8 af[4], bfr[4];
      const int ck = kk * 4 + q4;
#pragma unroll
      for (int r = 0; r < 4; ++r) {
        const int R = wm * 64 + r * 16 + rr;
        af[r] = *(const bf16x8*)(As + R * 64 + ((ck ^ (R & 7)) << 3));
      }
#pragma unroll
      for (int c = 0; c < 4; ++c) {
        const int R = wn * 64 + c * 16 + rr;
        bfr[c] = *(const bf16x8*)(Bs + R * 64 + ((ck ^ (R & 7)) << 3));
      }
#pragma unroll
      for (int r = 0; r < 4; ++r)
#pragma unroll
        for (int c = 0; c < 4; ++c)
          acc[r][c] = __builtin_amdgcn_mfma_f32_16x16x32_bf16(af[r], bfr[c], acc[r][c], 0, 0, 0);
    }
  }

  // C/D frag: col = lane&15, row = (lane>>4)*4 + reg
  if (MODE == 0) {
#pragma unroll
    for (int r = 0; r < 4; ++r) {
#pragma unroll
      for (int c = 0; c < 4; ++c) {
        const int gr0 = m0 + wm * 64 + r * 16 + (q4 << 2);
        const int gc = n0 + wn * 64 + c * 16 + rr;
#pragma unroll
        for (int i = 0; i < 4; ++i)
          C[(size_t)(gr0 + i) * ldc + gc] = (CT)(acc[r][c][i] * scale);
      }
    }
  } else {
    const int cb0 = (n0 + wn * 64) >> 5;
#pragma unroll
    for (int r = 0; r < 4; ++r) {
#pragma unroll
      for (int i = 0; i < 4; ++i) {
        const int row = m0 + wm * 64 + r * 16 + (q4 << 2) + i;
        const unsigned mw0 = mrow[(row << 5) + cb0];
        const unsigned mw1 = mrow[(row << 5) + cb0 + 1];
        float ps = 0.0f;
#pragma unroll
        for (int c = 0; c < 4; ++c) {
          const int gc = n0 + wn * 64 + c * 16 + rr;
          const unsigned mw = (c >= 2) ? mw1 : mw0;
          const unsigned bit = (mw >> (((c & 1) << 4) + rr)) & 1u;
          float p = bit ? __expf(acc[r][c][i] * scale) : 0.0f;
          C[(size_t)row * ldc + gc] = (CT)p;
          ps += p;
        }
        ps += __shfl_xor(ps, 1); ps += __shfl_xor(ps, 2);
        ps += __shfl_xor(ps, 4); ps += __shfl_xor(ps, 8);
        if (rr == 0) atomicAdd(sumrow + row, ps);
      }
    }
  }
}

// P1 job: lin in [0,12832) — cvt x,st,Wp; transpose Wq,Wk,Wv; mask; zero sums.
__device__ __forceinline__ void prep_work(
    int lin,
    const float* __restrict__ x, const float* __restrict__ st,
    const float* __restrict__ Wp, const float* __restrict__ Wq,
    const float* __restrict__ Wk, const float* __restrict__ Wv,
    const int* __restrict__ mask,
    bf16* __restrict__ xb, bf16* __restrict__ stb, bf16* __restrict__ wpb,
    bf16* __restrict__ WqT, bf16* __restrict__ WkT, bf16* __restrict__ WvT,
    unsigned* __restrict__ mbits, float* __restrict__ sums)
{
  const int t = threadIdx.x;
  if (lin < 6144) {
    const float* s; bf16* d;
    switch (lin >> 11) {
      case 0: s = x; d = xb; break;
      case 1: s = st; d = stb; break;
      default: s = Wp; d = wpb; break;
    }
    const int i = ((lin & 2047) * 256 + t) * 4;
    float4 v = *(const float4*)(s + i);
    bf16x4 o;
    o[0] = (bf16)v.x; o[1] = (bf16)v.y; o[2] = (bf16)v.z; o[3] = (bf16)v.w;
    *(bf16x4*)(d + i) = o;
  } else if (lin < 12288) {
    const int tid2 = lin - 6144;
    const float* s; bf16* d;
    switch (tid2 >> 11) {
      case 0: s = Wq; d = WqT; break;
      case 1: s = Wk; d = WkT; break;
      default: s = Wv; d = WvT; break;
    }
    const int gid = (tid2 & 2047) * 256 + t;      // [0, 524288)
    const int e0 = (gid & 127) * 4;
    const int dd = (gid >> 7) & 511;
    const int h = gid >> 16;
    const float* src = s + (size_t)h * 262144 + (size_t)e0 * 512 + dd;
    bf16x4 o;
    o[0] = (bf16)src[0];
    o[1] = (bf16)src[512];
    o[2] = (bf16)src[1024];
    o[3] = (bf16)src[1536];
    *(bf16x4*)(d + (size_t)h * 262144 + (size_t)dd * 512 + e0) = o;
  } else if (lin < 12800) {
    const int gid = (lin - 12288) * 256 + t;      // [0, 131072)
    const int* src = mask + (size_t)gid * 32;
    unsigned bits = 0;
#pragma unroll
    for (int j = 0; j < 32; j += 4) {
      int4 v = *(const int4*)(src + j);
      if (v.x) bits |= 1u << j;
      if (v.y) bits |= 1u << (j + 1);
      if (v.z) bits |= 1u << (j + 2);
      if (v.w) bits |= 1u << (j + 3);
    }
    mbits[gid] = bits;
  } else {
    const int i = ((lin - 12800) * 256 + t) * 4;  // [0, 32768) floats
    *(float4*)(sums + i) = make_float4(0.f, 0.f, 0.f, 0.f);
  }
}

// P5 job: lin in [0,512) — out_part[hp] += sinv_h ⊙ (P_h·VWT_h^T), 2 heads.
__device__ __forceinline__ void pvw_work(
    int lin, bf16* As, bf16* Bs,
    const bf16* __restrict__ P, const bf16* __restrict__ VWT,
    const float* __restrict__ sums, float* __restrict__ part)
{
  const int z = ((lin >> 8) << 3) | (lin & 7);    // [0,16)
  const int j = (lin >> 3) & 31;
  const int zb = z >> 2, hp = z & 3;
  const int m0 = (j >> 2) * 128, n0 = (j & 3) * 128;
  const int t = threadIdx.x;
  const int lane = t & 63, w = t >> 6;
  const int wm = w >> 1, wn = w & 1;
  const int srow = t >> 3, schunk = (t & 7) ^ (srow & 7);
  const int rr = lane & 15, q4 = lane >> 4;
  bf16* Als = As + t * 8;
  bf16* Bls = Bs + t * 8;

  f32x4 accO[4][4] = {};

#pragma unroll
  for (int hh = 0; hh < 2; ++hh) {
    const int h = hp * 2 + hh;
    const bf16* Ag = P + (size_t)zb * 8388608 + (size_t)h * 1048576
                       + (size_t)(m0 + srow) * 1024 + schunk * 8;
    const bf16* Bg = VWT + (size_t)zb * 4194304 + (size_t)h * 524288
                        + (size_t)(n0 + srow) * 1024 + schunk * 8;
    f32x4 acc[4][4] = {};
    for (int kt = 0; kt < 16; ++kt) {
      __syncthreads();
#pragma unroll
      for (int i = 0; i < 4; ++i) {
        gload_lds16(Ag + (size_t)(32 * i) * 1024, Als + i * 2048);
        gload_lds16(Bg + (size_t)(32 * i) * 1024, Bls + i * 2048);
      }
      Ag += 64; Bg += 64;
      __syncthreads();
#pragma unroll
      for (int kk = 0; kk < 2; ++kk) {
        bf16x8 af[4], bfr[4];
        const int ck = kk * 4 + q4;
#pragma unroll
        for (int r = 0; r < 4; ++r) {
          const int R = wm * 64 + r * 16 + rr;
          af[r] = *(const bf16x8*)(As + R * 64 + ((ck ^ (R & 7)) << 3));
        }
#pragma unroll
        for (int c = 0; c < 4; ++c) {
          const int R = wn * 64 + c * 16 + rr;
          bfr[c] = *(const bf16x8*)(Bs + R * 64 + ((ck ^ (R & 7)) << 3));
        }
#pragma unroll
        for (int r = 0; r < 4; ++r)
#pragma unroll
          for (int c = 0; c < 4; ++c)
            acc[r][c] = __builtin_amdgcn_mfma_f32_16x16x32_bf16(af[r], bfr[c], acc[r][c], 0, 0, 0);
      }
    }
    const float* srs = sums + ((size_t)zb * 8 + h) * 1024;
#pragma unroll
    for (int r = 0; r < 4; ++r) {
#pragma unroll
      for (int i = 0; i < 4; ++i) {
        const float inv = 1.0f / srs[m0 + wm * 64 + r * 16 + (q4 << 2) + i];
#pragma unroll
        for (int c = 0; c < 4; ++c)
          accO[r][c][i] += acc[r][c][i] * inv;
      }
    }
  }

  float* Cp = part + (size_t)hp * 2097152 + (size_t)zb * 524288;
#pragma unroll
  for (int r = 0; r < 4; ++r) {
#pragma unroll
    for (int c = 0; c < 4; ++c) {
      const int gr0 = m0 + wm * 64 + r * 16 + (q4 << 2);
      const int gc = n0 + wn * 64 + c * 16 + rr;
#pragma unroll
      for (int i = 0; i < 4; ++i)
        Cp[(size_t)(gr0 + i) * 512 + gc] = accO[r][c][i];
    }
  }
}

// ---- The single cooperative kernel. grid = G (mult of 8, <=768), 256 thr. ----
__global__ __launch_bounds__(256, 3) void fused_kernel(
    const float* __restrict__ x, const float* __restrict__ st,
    const int* __restrict__ mask,
    const float* __restrict__ Wq, const float* __restrict__ Wk,
    const float* __restrict__ Wv, const float* __restrict__ Wp,
    bf16* __restrict__ xb, bf16* __restrict__ stb, bf16* __restrict__ wpb,
    bf16* __restrict__ WqT, bf16* __restrict__ WkT, bf16* __restrict__ WvT,
    bf16* __restrict__ U, bf16* __restrict__ Mt,
    bf16* __restrict__ tq, bf16* __restrict__ VWT, bf16* __restrict__ P,
    unsigned* __restrict__ mbits, float* __restrict__ sums,
    float* __restrict__ part, float* __restrict__ out, float scale)
{
  __shared__ bf16 As[128 * 64];
  __shared__ bf16 Bs[128 * 64];
  cg::grid_group grid = cg::this_grid();
  const int bid = blockIdx.x;
  const int G = gridDim.x;           // multiple of 8 -> j%8 == bid%8 preserved

  // ---- P1: prep ----
  for (int j = bid; j < 12832; j += G)
    prep_work(j, x, st, Wp, Wq, Wk, Wv, mask,
              xb, stb, wpb, WqT, WkT, WvT, mbits, sums);
  grid.sync();

  // ---- P2: combine — Mt_h = WkT_h.WqT_h^T, U_h = Wp_h.WvT_h^T ----
  for (int j = bid; j < 256; j += G) {
    const int g = (j & 7) * 32 + (j >> 3);
    const int h = (g >> 4) & 7;
    const int tile = g & 15;                       // 4m x 4n
    if (g < 128) {
      gemm_body<bf16, 0>(As, Bs, WkT + (size_t)h * 262144, WqT + (size_t)h * 262144,
          Mt + (size_t)h * 262144, 512, 512, 512, 512,
          (tile >> 2) * 128, (tile & 3) * 128, 1.0f, nullptr, nullptr);
    } else {
      gemm_body<bf16, 0>(As, Bs, wpb + (size_t)h * 512, WvT + (size_t)h * 262144,
          U + (size_t)h * 262144, 512, 4096, 512, 512,
          (tile >> 2) * 128, (tile & 3) * 128, 1.0f, nullptr, nullptr);
    }
  }
  grid.sync();

  // ---- P3: stage2 — t = x.Mt^T, VWT = U.states^T ----
  for (int j = bid; j < 2048; j += G) {
    const int g = (j & 7) * 256 + (j >> 3);
    if (g < 1024) {
      const int z = g >> 5;
      const int tile = g & 31;                     // 8m x 4n
      const size_t zb = z >> 3, zh = z & 7;
      gemm_body<bf16, 0>(As, Bs, xb + zb * 524288, Mt + zh * 262144,
          tq + (size_t)z * 524288, 512, 512, 512, 512,
          (tile >> 2) * 128, (tile & 3) * 128, 1.0f, nullptr, nullptr);
    } else {
      const int g2 = g - 1024;
      const int z = g2 >> 5;
      const int jj = g2 & 31;                      // 4m x 8n
      const size_t zb = z >> 3, zh = z & 7;
      gemm_body<bf16, 0>(As, Bs, U + zh * 262144, stb + zb * 524288,
          VWT + zb * 4194304 + zh * 524288, 512, 512, 512, 1024,
          (jj >> 3) * 128, (jj & 7) * 128, 1.0f, nullptr, nullptr);
    }
  }
  grid.sync();

  // ---- P4: big — P = mask ? exp(scale * t.states^T) : 0, + row sums ----
  for (int j = bid; j < 2048; j += G) {
    const int g = (j & 7) * 256 + (j >> 3);
    const int z = g >> 6;                          // [0,32)
    const int jj = g & 63;                         // 8m x 8n
    const size_t zb = z >> 3, zh = z & 7;
    gemm_body<bf16, 1>(As, Bs,
        tq + (size_t)z * 524288,
        stb + zb * 524288,
        P + zb * 8388608 + zh * 1048576,
        512, 512, 512, 1024,
        (jj >> 3) * 128, (jj & 7) * 128, scale,
        mbits + (zb << 15), sums + ((size_t)z << 10));
  }
  grid.sync();

  // ---- P5: pvw ----
  for (int j = bid; j < 512; j += G)
    pvw_work(j, As, Bs, P, VWT, sums, part);
  grid.sync();

  // ---- P6: out = part0+part1+part2+part3 ----
  for (int i4 = bid * 256 + (int)threadIdx.x; i4 < 524288; i4 += G * 256) {
    const size_t i = (size_t)i4 * 4;
    float4 a = *(const float4*)(part + i);
    float4 b = *(const float4*)(part + 2097152 + i);
    float4 c = *(const float4*)(part + 4194304 + i);
    float4 d = *(const float4*)(part + 6291456 + i);
    float4 o;
    o.x = (a.x + b.x) + (c.x + d.x);
    o.y = (a.y + b.y) + (c.y + d.y);
    o.z = (a.z + b.z) + (c.z + d.z);
    o.w = (a.w + b.w) + (c.w + d.w);
    *(float4*)(out + i) = o;
  }
}

extern "C" void kernel_launch(void* const* d_in, const int* in_sizes, int n_in,
                              void* d_out, int out_size, void* d_ws, size_t ws_size,
                              hipStream_t stream) {
  const float* x    = (const float*)d_in[0];
  const float* st   = (const float*)d_in[1];
  const int*   mask = (const int*)d_in[2];
  const float* Wq   = (const float*)d_in[3];
  const float* Wk   = (const float*)d_in[4];
  const float* Wv   = (const float*)d_in[5];
  const float* Wp   = (const float*)d_in[6];
  float* out = (float*)d_out;

  char* ws = (char*)d_ws;
  const size_t MB = 1048576;
  bf16* xb  = (bf16*)(ws);               // 4MB
  bf16* stb = (bf16*)(ws + 4 * MB);      // 4MB (live through big)
  bf16* wpb = (bf16*)(ws + 8 * MB);      // 4MB
  bf16* WqT = (bf16*)(ws + 12 * MB);     // 4MB [8,512,512] Wq transposed
  bf16* WkT = (bf16*)(ws + 16 * MB);     // 4MB
  bf16* WvT = (bf16*)(ws + 20 * MB);     // 4MB
  bf16* U   = (bf16*)(ws + 24 * MB);     // 4MB [8,512,512] Wp_h.Wv_h
  bf16* Mt  = (bf16*)(ws + 28 * MB);     // 4MB [8,512,512] Wk_h^T.Wq_h
  bf16* tq  = (bf16*)(ws + 32 * MB);     // 32MB [4,8,1024,512]; dead after big
  bf16* VWT = (bf16*)(ws + 64 * MB);     // 32MB [4,8,512,1024]
  bf16* P   = (bf16*)(ws + 96 * MB);     // 64MB exp(scores)
  unsigned* mbits = (unsigned*)(ws + 160 * MB);  // 512KB
  float*    sums  = (float*)(ws + 161 * MB);     // 128KB
  float*    part  = (float*)(ws + 32 * MB);      // 32MB fp32 (over tq)

  float scale = 0.04419417382415922f;  // 1/sqrt(512)

  // Co-residency-safe grid: occupancy query, clamp to 768, multiple of 8.
  int nb = 0;
  hipError_t e = hipOccupancyMaxActiveBlocksPerMultiprocessor(
      &nb, (const void*)fused_kernel, 256, 0);
  if (e != hipSuccess || nb < 1) nb = 1;
  int grid = nb * 256;
  if (grid > 768) grid = 768;
  grid &= ~7;
  if (grid < 8) grid = 8;

  void* args[] = {
    (void*)&x, (void*)&st, (void*)&mask, (void*)&Wq, (void*)&Wk,
    (void*)&Wv, (void*)&Wp,
    (void*)&xb, (void*)&stb, (void*)&wpb, (void*)&WqT, (void*)&WkT,
    (void*)&WvT, (void*)&U, (void*)&Mt, (void*)&tq, (void*)&VWT, (void*)&P,
    (void*)&mbits, (void*)&sums, (void*)&part, (void*)&out, (void*)&scale
  };
  hipLaunchCooperativeKernel((const void*)fused_kernel, dim3(grid), dim3(256),
                             args, 0, stream);
}

// Round 9
// 307.195 us; speedup vs baseline: 2.0419x; 2.0419x over previous
//
#include <hip/hip_runtime.h>
#include <hip/hip_bf16.h>
#include <cstdint>
#include <cstddef>

// B=4, LQ=LK=1024, D=512, H=8. fp32 in/out; bf16 MFMA compute.
// R15: R13 structure (best measured: Mt/U algebra + proven 2-barrier 128x128
// engine, 32KB LDS, ~3 blocks/CU) with the tail amputated: pvw atomically
// accumulates fp32 into out (each element hit by exactly 4 hp-blocks,
// fire-and-forget), killing the reduce4 dispatch, its ~10us boundary, and the
// 64MB part round-trip. out is zeroed in prep. R14's cooperative fusion is
// reverted (grid.sync cost ~100us/sync on 768 blocks — measured 751us fused).

typedef __bf16 bf16;
typedef __bf16 bf16x4 __attribute__((ext_vector_type(4)));
typedef __bf16 bf16x8 __attribute__((ext_vector_type(8)));
typedef float f32x4 __attribute__((ext_vector_type(4)));

__device__ inline void gload_lds16(const void* g, void* l) {
  __builtin_amdgcn_global_load_lds(
      (const __attribute__((address_space(1))) void*)g,
      (__attribute__((address_space(3))) void*)l, 16, 0, 0);
}

// Tile body: C[128,128] at (m0,n0) of scale*(A . B^T). BK=64, 256 thr.
// LDS swizzle: global 16B-chunk c of row r lives at slot c ^ (r&7).
// MODE 0: C = acc*scale (CT).
// MODE 1: P = maskbit ? exp(acc*scale) : 0 -> C (bf16); atomicAdd row sums.
// (verbatim R7/R13 body — 0 bank conflicts measured, best engine so far)
template <typename CT, int MODE>
__device__ __forceinline__ void gemm_body(
    bf16* As, bf16* Bs,
    const bf16* __restrict__ A, const bf16* __restrict__ B, CT* __restrict__ C,
    int K, int lda, int ldb, int ldc, int m0, int n0, float scale,
    const unsigned* __restrict__ mrow, float* __restrict__ sumrow)
{
  const int t = threadIdx.x;
  const int lane = t & 63, w = t >> 6;
  const int wm = w >> 1, wn = w & 1;

  const int srow = t >> 3;                       // 0..31
  const int schunk = (t & 7) ^ (srow & 7);       // swizzled source chunk
  const bf16* Ag = A + (size_t)(m0 + srow) * lda + schunk * 8;
  const bf16* Bg = B + (size_t)(n0 + srow) * ldb + schunk * 8;
  bf16* Als = As + t * 8;
  bf16* Bls = Bs + t * 8;

  f32x4 acc[4][4] = {};
  const int rr = lane & 15;
  const int q4 = lane >> 4;

  const int kIters = K >> 6;
  for (int kt = 0; kt < kIters; ++kt) {
    __syncthreads();
#pragma unroll
    for (int i = 0; i < 4; ++i) {
      gload_lds16(Ag + (size_t)(32 * i) * lda, Als + i * 2048);
      gload_lds16(Bg + (size_t)(32 * i) * ldb, Bls + i * 2048);
    }
    Ag += 64; Bg += 64;
    __syncthreads();

#pragma unroll
    for (int kk = 0; kk < 2; ++kk) {
      bf16x8 af[4], bfr[4];
      const int ck = kk * 4 + q4;
#pragma unroll
      for (int r = 0; r < 4; ++r) {
        const int R = wm * 64 + r * 16 + rr;
        af[r] = *(const bf16x8*)(As + R * 64 + ((ck ^ (R & 7)) << 3));
      }
#pragma unroll
      for (int c = 0; c < 4; ++c) {
        const int R = wn * 64 + c * 16 + rr;
        bfr[c] = *(const bf16x8*)(Bs + R * 64 + ((ck ^ (R & 7)) << 3));
      }
#pragma unroll
      for (int r = 0; r < 4; ++r)
#pragma unroll
        for (int c = 0; c < 4; ++c)
          acc[r][c] = __builtin_amdgcn_mfma_f32_16x16x32_bf16(af[r], bfr[c], acc[r][c], 0, 0, 0);
    }
  }

  // C/D frag: col = lane&15, row = (lane>>4)*4 + reg
  if (MODE == 0) {
#pragma unroll
    for (int r = 0; r < 4; ++r) {
#pragma unroll
      for (int c = 0; c < 4; ++c) {
        const int gr0 = m0 + wm * 64 + r * 16 + (q4 << 2);
        const int gc = n0 + wn * 64 + c * 16 + rr;
#pragma unroll
        for (int i = 0; i < 4; ++i)
          C[(size_t)(gr0 + i) * ldc + gc] = (CT)(acc[r][c][i] * scale);
      }
    }
  } else {
    const int cb0 = (n0 + wn * 64) >> 5;
#pragma unroll
    for (int r = 0; r < 4; ++r) {
#pragma unroll
      for (int i = 0; i < 4; ++i) {
        const int row = m0 + wm * 64 + r * 16 + (q4 << 2) + i;
        const unsigned mw0 = mrow[(row << 5) + cb0];
        const unsigned mw1 = mrow[(row << 5) + cb0 + 1];
        float ps = 0.0f;
#pragma unroll
        for (int c = 0; c < 4; ++c) {
          const int gc = n0 + wn * 64 + c * 16 + rr;
          const unsigned mw = (c >= 2) ? mw1 : mw0;
          const unsigned bit = (mw >> (((c & 1) << 4) + rr)) & 1u;
          float p = bit ? __expf(acc[r][c][i] * scale) : 0.0f;
          C[(size_t)row * ldc + gc] = (CT)p;
          ps += p;
        }
        ps += __shfl_xor(ps, 1); ps += __shfl_xor(ps, 2);
        ps += __shfl_xor(ps, 4); ps += __shfl_xor(ps, 8);
        if (rr == 0) atomicAdd(sumrow + row, ps);
      }
    }
  }
}

// ---- Dispatch 1: prep (cvt x,st,Wp + transpose Wq,Wk,Wv + mask + zero
// sums + zero out). grid 14880x256. ----
__global__ __launch_bounds__(256) void prep_kernel(
    const float* __restrict__ x, const float* __restrict__ st,
    const float* __restrict__ Wp, const float* __restrict__ Wq,
    const float* __restrict__ Wk, const float* __restrict__ Wv,
    const int* __restrict__ mask,
    bf16* __restrict__ xb, bf16* __restrict__ stb, bf16* __restrict__ wpb,
    bf16* __restrict__ WqT, bf16* __restrict__ WkT, bf16* __restrict__ WvT,
    unsigned* __restrict__ mbits, float* __restrict__ sums,
    float* __restrict__ out)
{
  const int lin = blockIdx.x;
  const int t = threadIdx.x;
  if (lin < 6144) {
    const float* s; bf16* d;
    switch (lin >> 11) {
      case 0: s = x; d = xb; break;
      case 1: s = st; d = stb; break;
      default: s = Wp; d = wpb; break;
    }
    const int i = ((lin & 2047) * 256 + t) * 4;
    float4 v = *(const float4*)(s + i);
    bf16x4 o;
    o[0] = (bf16)v.x; o[1] = (bf16)v.y; o[2] = (bf16)v.z; o[3] = (bf16)v.w;
    *(bf16x4*)(d + i) = o;
  } else if (lin < 12288) {
    // WT[h][d][e] = W[h][e][d]
    const int tid = lin - 6144;
    const float* s; bf16* d;
    switch (tid >> 11) {
      case 0: s = Wq; d = WqT; break;
      case 1: s = Wk; d = WkT; break;
      default: s = Wv; d = WvT; break;
    }
    const int gid = (tid & 2047) * 256 + t;       // [0, 524288)
    const int e0 = (gid & 127) * 4;
    const int dd = (gid >> 7) & 511;
    const int h = gid >> 16;
    const float* src = s + (size_t)h * 262144 + (size_t)e0 * 512 + dd;
    bf16x4 o;
    o[0] = (bf16)src[0];
    o[1] = (bf16)src[512];
    o[2] = (bf16)src[1024];
    o[3] = (bf16)src[1536];
    *(bf16x4*)(d + (size_t)h * 262144 + (size_t)dd * 512 + e0) = o;
  } else if (lin < 12800) {
    const int gid = (lin - 12288) * 256 + t;      // [0, 131072)
    const int* src = mask + (size_t)gid * 32;
    unsigned bits = 0;
#pragma unroll
    for (int j = 0; j < 32; j += 4) {
      int4 v = *(const int4*)(src + j);
      if (v.x) bits |= 1u << j;
      if (v.y) bits |= 1u << (j + 1);
      if (v.z) bits |= 1u << (j + 2);
      if (v.w) bits |= 1u << (j + 3);
    }
    mbits[gid] = bits;
  } else if (lin < 12832) {
    const int i = ((lin - 12800) * 256 + t) * 4;  // [0, 32768) floats
    *(float4*)(sums + i) = make_float4(0.f, 0.f, 0.f, 0.f);
  } else {
    const int i = ((lin - 12832) * 256 + t) * 4;  // [0, 2097152) floats
    *(float4*)(out + i) = make_float4(0.f, 0.f, 0.f, 0.f);
  }
}

// ---- Dispatch 2: combine — Mt_h = WkT_h.WqT_h^T, U_h = Wp_h.WvT_h^T.
// grid 256x256 (8 XCD x 32). ----
__global__ __launch_bounds__(256) void combine_kernel(
    const bf16* __restrict__ WqT, const bf16* __restrict__ WkT,
    const bf16* __restrict__ wpb, const bf16* __restrict__ WvT,
    bf16* __restrict__ Mt, bf16* __restrict__ U)
{
  __shared__ bf16 As[128 * 64];
  __shared__ bf16 Bs[128 * 64];
  const int bid = blockIdx.x;
  const int g = (bid & 7) * 32 + (bid >> 3);     // [0,256)
  const int h = (g >> 4) & 7;
  const int tile = g & 15;                       // 4m x 4n
  if (g < 128) {
    // Mt_h[d',d] = sum_e WkT[d',e] * WqT[d,e]
    gemm_body<bf16, 0>(As, Bs, WkT + (size_t)h * 262144, WqT + (size_t)h * 262144,
        Mt + (size_t)h * 262144, 512, 512, 512, 512,
        (tile >> 2) * 128, (tile & 3) * 128, 1.0f, nullptr, nullptr);
  } else {
    // U_h[e,d] = sum_e' Wp[e, h*512+e'] * WvT_h[d, e']
    gemm_body<bf16, 0>(As, Bs, wpb + (size_t)h * 512, WvT + (size_t)h * 262144,
        U + (size_t)h * 262144, 512, 4096, 512, 512,
        (tile >> 2) * 128, (tile & 3) * 128, 1.0f, nullptr, nullptr);
  }
}

// ---- Dispatch 3: stage2 — t_bh = x_b.Mt_h^T, VWT = U_h.states_b^T.
// grid 2048x256 (8 XCD x 256). ----
__global__ __launch_bounds__(256) void stage2_kernel(
    const bf16* __restrict__ xb, const bf16* __restrict__ stb,
    const bf16* __restrict__ Mt, const bf16* __restrict__ U,
    bf16* __restrict__ tq, bf16* __restrict__ VWT)
{
  __shared__ bf16 As[128 * 64];
  __shared__ bf16 Bs[128 * 64];
  const int bid = blockIdx.x;
  const int g = (bid & 7) * 256 + (bid >> 3);    // [0,2048)
  if (g < 1024) {
    // t[z][l,d'] = sum_d x_b[l,d] Mt_h[d',d]; z = zb*8+zh
    const int z = g >> 5;
    const int tile = g & 31;                     // 8m x 4n
    const size_t zb = z >> 3, zh = z & 7;
    gemm_body<bf16, 0>(As, Bs, xb + zb * 524288, Mt + zh * 262144,
        tq + (size_t)z * 524288, 512, 512, 512, 512,
        (tile >> 2) * 128, (tile & 3) * 128, 1.0f, nullptr, nullptr);
  } else {
    // VWT[b,h][e,s] = U_h . states_b^T
    const int g2 = g - 1024;
    const int z = g2 >> 5;
    const int j = g2 & 31;                       // 4m x 8n
    const size_t zb = z >> 3, zh = z & 7;
    gemm_body<bf16, 0>(As, Bs, U + zh * 262144, stb + zb * 524288,
        VWT + zb * 4194304 + zh * 524288, 512, 512, 512, 1024,
        (j >> 3) * 128, (j & 7) * 128, 1.0f, nullptr, nullptr);
  }
}

// ---- Dispatch 4: big — P = mask ? exp(scale * t.states^T) : 0, + row sums.
// grid 2048x256 (8 XCD x 256). ----
__global__ __launch_bounds__(256) void big_kernel(
    const bf16* __restrict__ tq, const bf16* __restrict__ stb,
    bf16* __restrict__ P,
    const unsigned* __restrict__ mbits, float* __restrict__ sums, float scale)
{
  __shared__ bf16 As[128 * 64];
  __shared__ bf16 Bs[128 * 64];
  const int bid = blockIdx.x;
  const int g = (bid & 7) * 256 + (bid >> 3);    // [0,2048)
  const int z = g >> 6;                          // [0,32)
  const int j = g & 63;                          // 8m x 8n
  const size_t zb = z >> 3, zh = z & 7;
  gemm_body<bf16, 1>(As, Bs,
      tq + (size_t)z * 524288,
      stb + zb * 524288,
      P + zb * 8388608 + zh * 1048576,
      512, 512, 512, 1024,
      (j >> 3) * 128, (j & 7) * 128, scale,
      mbits + (zb << 15), sums + ((size_t)z << 10));
}

// ---- Dispatch 5: pvw — out += sinv_h ⊙ (P_h·VWT_h^T), 2 heads per block,
// fp32 atomicAdd into out (4 hp-blocks per element). grid 512x256. ----
__global__ __launch_bounds__(256) void pvw_kernel(
    const bf16* __restrict__ P, const bf16* __restrict__ VWT,
    const float* __restrict__ sums, float* __restrict__ out)
{
  __shared__ bf16 As[128 * 64];
  __shared__ bf16 Bs[128 * 64];
  const int lin = blockIdx.x;
  const int z = ((lin >> 8) << 3) | (lin & 7);    // [0,16)
  const int j = (lin >> 3) & 31;
  const int zb = z >> 2, hp = z & 3;
  const int m0 = (j >> 2) * 128, n0 = (j & 3) * 128;
  const int t = threadIdx.x;
  const int lane = t & 63, w = t >> 6;
  const int wm = w >> 1, wn = w & 1;
  const int srow = t >> 3, schunk = (t & 7) ^ (srow & 7);
  const int rr = lane & 15, q4 = lane >> 4;
  bf16* Als = As + t * 8;
  bf16* Bls = Bs + t * 8;

  f32x4 accO[4][4] = {};

#pragma unroll
  for (int hh = 0; hh < 2; ++hh) {
    const int h = hp * 2 + hh;
    const bf16* Ag = P + (size_t)zb * 8388608 + (size_t)h * 1048576
                       + (size_t)(m0 + srow) * 1024 + schunk * 8;
    const bf16* Bg = VWT + (size_t)zb * 4194304 + (size_t)h * 524288
                        + (size_t)(n0 + srow) * 1024 + schunk * 8;
    f32x4 acc[4][4] = {};
    for (int kt = 0; kt < 16; ++kt) {
      __syncthreads();
#pragma unroll
      for (int i = 0; i < 4; ++i) {
        gload_lds16(Ag + (size_t)(32 * i) * 1024, Als + i * 2048);
        gload_lds16(Bg + (size_t)(32 * i) * 1024, Bls + i * 2048);
      }
      Ag += 64; Bg += 64;
      __syncthreads();
#pragma unroll
      for (int kk = 0; kk < 2; ++kk) {
        bf16x8 af[4], bfr[4];
        const int ck = kk * 4 + q4;
#pragma unroll
        for (int r = 0; r < 4; ++r) {
          const int R = wm * 64 + r * 16 + rr;
          af[r] = *(const bf16x8*)(As + R * 64 + ((ck ^ (R & 7)) << 3));
        }
#pragma unroll
        for (int c = 0; c < 4; ++c) {
          const int R = wn * 64 + c * 16 + rr;
          bfr[c] = *(const bf16x8*)(Bs + R * 64 + ((ck ^ (R & 7)) << 3));
        }
#pragma unroll
        for (int r = 0; r < 4; ++r)
#pragma unroll
          for (int c = 0; c < 4; ++c)
            acc[r][c] = __builtin_amdgcn_mfma_f32_16x16x32_bf16(af[r], bfr[c], acc[r][c], 0, 0, 0);
      }
    }
    const float* srs = sums + ((size_t)zb * 8 + h) * 1024;
#pragma unroll
    for (int r = 0; r < 4; ++r) {
#pragma unroll
      for (int i = 0; i < 4; ++i) {
        const float inv = 1.0f / srs[m0 + wm * 64 + r * 16 + (q4 << 2) + i];
#pragma unroll
        for (int c = 0; c < 4; ++c)
          accO[r][c][i] += acc[r][c][i] * inv;
      }
    }
  }

  // Fire-and-forget fp32 atomic accumulate into out (zeroed in prep).
  float* Ob = out + (size_t)zb * 524288;
#pragma unroll
  for (int r = 0; r < 4; ++r) {
#pragma unroll
    for (int c = 0; c < 4; ++c) {
      const int gr0 = m0 + wm * 64 + r * 16 + (q4 << 2);
      const int gc = n0 + wn * 64 + c * 16 + rr;
#pragma unroll
      for (int i = 0; i < 4; ++i)
        atomicAdd(Ob + (size_t)(gr0 + i) * 512 + gc, accO[r][c][i]);
    }
  }
}

extern "C" void kernel_launch(void* const* d_in, const int* in_sizes, int n_in,
                              void* d_out, int out_size, void* d_ws, size_t ws_size,
                              hipStream_t stream) {
  const float* x    = (const float*)d_in[0];
  const float* st   = (const float*)d_in[1];
  const int*   mask = (const int*)d_in[2];
  const float* Wq   = (const float*)d_in[3];
  const float* Wk   = (const float*)d_in[4];
  const float* Wv   = (const float*)d_in[5];
  const float* Wp   = (const float*)d_in[6];
  float* out = (float*)d_out;

  char* ws = (char*)d_ws;
  const size_t MB = 1048576;
  bf16* xb  = (bf16*)(ws);               // 4MB
  bf16* stb = (bf16*)(ws + 4 * MB);      // 4MB (live through big)
  bf16* wpb = (bf16*)(ws + 8 * MB);      // 4MB
  bf16* WqT = (bf16*)(ws + 12 * MB);     // 4MB [8,512,512] Wq transposed
  bf16* WkT = (bf16*)(ws + 16 * MB);     // 4MB
  bf16* WvT = (bf16*)(ws + 20 * MB);     // 4MB
  bf16* U   = (bf16*)(ws + 24 * MB);     // 4MB [8,512,512] Wp_h.Wv_h
  bf16* Mt  = (bf16*)(ws + 28 * MB);     // 4MB [8,512,512] Wk_h^T.Wq_h
  bf16* tq  = (bf16*)(ws + 32 * MB);     // 32MB [4,8,1024,512]; dead after big
  bf16* VWT = (bf16*)(ws + 64 * MB);     // 32MB [4,8,512,1024]
  bf16* P   = (bf16*)(ws + 96 * MB);     // 64MB exp(scores)
  unsigned* mbits = (unsigned*)(ws + 160 * MB);  // 512KB
  float*    sums  = (float*)(ws + 161 * MB);     // 128KB

  dim3 blk(256);
  const float scale = 0.04419417382415922f;  // 1/sqrt(512)

  prep_kernel<<<dim3(14880), blk, 0, stream>>>(x, st, Wp, Wq, Wk, Wv, mask,
      xb, stb, wpb, WqT, WkT, WvT, mbits, sums, out);

  combine_kernel<<<dim3(256), blk, 0, stream>>>(WqT, WkT, wpb, WvT, Mt, U);

  stage2_kernel<<<dim3(2048), blk, 0, stream>>>(xb, stb, Mt, U, tq, VWT);

  big_kernel<<<dim3(2048), blk, 0, stream>>>(tq, stb, P, mbits, sums, scale);

  pvw_kernel<<<dim3(512), blk, 0, stream>>>(P, VWT, sums, out);
}